// Round 5
// baseline (277.953 us; speedup 1.0000x reference)
//
#include <hip/hip_runtime.h>

#define BN 16384   // B*N rows
#define NN 2048    // N
#define DD 64      // hidden
#define CC 16      // classes
#define KS1 8      // K-splits gemm1
#define KS2 16     // K-splits gemm2

typedef short bf16x8 __attribute__((ext_vector_type(8)));
typedef float f32x4 __attribute__((ext_vector_type(4)));
typedef unsigned short u16x4 __attribute__((ext_vector_type(4)));

__device__ __forceinline__ f32x4 mfma16(bf16x8 a, bf16x8 b, f32x4 c) {
  return __builtin_amdgcn_mfma_f32_16x16x32_bf16(a, b, c, 0, 0, 0);
}
__device__ __forceinline__ unsigned short f2bf(float f) {   // RNE
  unsigned u = __float_as_uint(f);
  return (unsigned short)((u + 0x7FFFu + ((u >> 16) & 1u)) >> 16);
}
__device__ __forceinline__ float bf2f(unsigned short h) {
  return __uint_as_float(((unsigned)h) << 16);
}

// ---------------- threefry-2x32 dropout mask (JAX key(42)) ----------------
__device__ __forceinline__ unsigned tf_bits(unsigned i) {
  unsigned x0 = 0u;
  unsigned x1 = i;
  const unsigned k0 = 0u, k1 = 42u, k2 = 0x1BD11BDAu ^ 0u ^ 42u;
  x0 += k0; x1 += k1;
#define TFR(r) { x0 += x1; x1 = (x1 << (r)) | (x1 >> (32 - (r))); x1 ^= x0; }
  TFR(13) TFR(15) TFR(26) TFR(6)
  x0 += k1; x1 += k2 + 1u;
  TFR(17) TFR(29) TFR(16) TFR(24)
  x0 += k2; x1 += k0 + 2u;
  TFR(13) TFR(15) TFR(26) TFR(6)
  x0 += k0; x1 += k1 + 3u;
  TFR(17) TFR(29) TFR(16) TFR(24)
  x0 += k1; x1 += k2 + 4u;
  TFR(13) TFR(15) TFR(26) TFR(6)
  x0 += k2; x1 += k0 + 5u;
#undef TFR
  return x0 ^ x1;
}

// ==================== bf16-MFMA PATH ====================

// ---- k_deg: row degrees + A -> bf16 (single pass over A) -----------------
__global__ __launch_bounds__(256) void k_deg(const float* __restrict__ A,
    float* __restrict__ dis, unsigned short* __restrict__ Abf)
{
  const int w = threadIdx.x >> 6, lane = threadIdx.x & 63;
  const size_t row = (size_t)blockIdx.x * 4 + w;
  const float4* Arow = (const float4*)(A + row * NN);
  unsigned short* Brow = Abf + row * NN;
  float s = 0.f;
#pragma unroll
  for (int it = 0; it < 8; ++it) {
    float4 v = Arow[lane + 64 * it];
    s += (v.x + v.y) + (v.z + v.w);
    u16x4 p = { f2bf(v.x), f2bf(v.y), f2bf(v.z), f2bf(v.w) };
    *(u16x4*)(Brow + lane * 4 + it * 256) = p;
  }
#pragma unroll
  for (int m = 32; m; m >>= 1) s += __shfl_xor(s, m, 64);
  if (lane == 0) dis[row] = 1.0f / sqrtf(s + 1.0f);   // A_tilda = A + I
}

// ---- k_xw1 (MFMA): Y1 = dis*(X@W1) -> row-major bf16 + transposed bf16 ---
// block = 4 waves; wave w: rows r0+w*16..+16, all 64 cols (4 N-tiles), K=64.
__global__ __launch_bounds__(256) void k_xw1(const float* __restrict__ X,
    const float* __restrict__ W1, const float* __restrict__ dis,
    unsigned short* __restrict__ Y1s, unsigned short* __restrict__ Y1sT)
{
  const int tid = threadIdx.x;
  const int w = __builtin_amdgcn_readfirstlane(tid >> 6);
  const int lane = tid & 63;
  const int m15 = lane & 15, quad = lane >> 4;
  const int r0 = blockIdx.x * 64;
  const int b = r0 >> 11, kr0 = r0 & (NN - 1);
  const int arow = r0 + w * 16 + m15;
  const f32x4 zero = 0.f;
  f32x4 acc[4];
#pragma unroll
  for (int t = 0; t < 4; ++t) acc[t] = zero;
#pragma unroll
  for (int ksx = 0; ksx < 2; ++ksx) {
    const float* xp = X + (size_t)arow * DD + ksx * 32 + quad * 8;
    float4 x0 = *(const float4*)xp;
    float4 x1 = *(const float4*)(xp + 4);
    bf16x8 af = { (short)f2bf(x0.x), (short)f2bf(x0.y), (short)f2bf(x0.z), (short)f2bf(x0.w),
                  (short)f2bf(x1.x), (short)f2bf(x1.y), (short)f2bf(x1.z), (short)f2bf(x1.w) };
#pragma unroll
    for (int t = 0; t < 4; ++t) {
      const float* wp = W1 + (size_t)(ksx * 32 + quad * 8) * DD + t * 16 + m15;
      bf16x8 bfr = { (short)f2bf(wp[0*DD]), (short)f2bf(wp[1*DD]), (short)f2bf(wp[2*DD]), (short)f2bf(wp[3*DD]),
                     (short)f2bf(wp[4*DD]), (short)f2bf(wp[5*DD]), (short)f2bf(wp[6*DD]), (short)f2bf(wp[7*DD]) };
      acc[t] = mfma16(af, bfr, acc[t]);
    }
  }
  // C layout: row = quad*4+r, col = t*16+m15
#pragma unroll
  for (int t = 0; t < 4; ++t)
#pragma unroll
    for (int r = 0; r < 4; ++r) {
      const int rowo = r0 + w * 16 + quad * 4 + r;
      const unsigned short v = f2bf(dis[rowo] * acc[t][r]);
      Y1s[(size_t)rowo * DD + t * 16 + m15] = v;
      Y1sT[((size_t)b * DD + t * 16 + m15) * NN + (kr0 + w * 16 + quad * 4 + r)] = v;
    }
}

// ---- k_gemm1: Z1[ks] = Abf @ Y1 (bf16 MFMA), 4M x 2N per wave, KS1=8 -----
// block = 4 waves = 256 rows x 32 cols; grid = 64 Mb x 2 Nhalf x 8 KS = 1024.
__global__ __launch_bounds__(256, 4) void k_gemm1(const unsigned short* __restrict__ Abf,
    const unsigned short* __restrict__ Y1sT, float* __restrict__ Z1)
{
  const int Mb = blockIdx.x >> 4;                 // 0..63 (256-row tiles)
  const int ns = (blockIdx.x >> 3) & 1;           // N half (32 cols)
  const int ks = blockIdx.x & 7;                  // K split (256 K)
  const int w = __builtin_amdgcn_readfirstlane((int)threadIdx.x >> 6);
  const int lane = threadIdx.x & 63;
  const int m15 = lane & 15, quad = lane >> 4;
  const int b = Mb >> 3;                          // 8 blocks per batch
  const int k0 = ks * 256 + quad * 8;
  const unsigned short* Ap[4];
#pragma unroll
  for (int m = 0; m < 4; ++m)
    Ap[m] = Abf + ((size_t)Mb * 256 + m * 64 + w * 16 + m15) * NN + k0;
  const unsigned short* Bp0 = Y1sT + ((size_t)b * DD + ns * 32 + m15) * NN + k0;
  const unsigned short* Bp1 = Bp0 + (size_t)16 * NN;
  const f32x4 zero = 0.f;
  f32x4 acc[4][2];
#pragma unroll
  for (int m = 0; m < 4; ++m) { acc[m][0] = zero; acc[m][1] = zero; }
  bf16x8 a[4], b0, b1;
#pragma unroll
  for (int m = 0; m < 4; ++m) a[m] = *(const bf16x8*)Ap[m];
  b0 = *(const bf16x8*)Bp0;
  b1 = *(const bf16x8*)Bp1;
#pragma unroll 1
  for (int kk = 0; kk < 8; ++kk) {
    const int off = (kk < 7) ? (kk + 1) * 32 : 0;  // wrap: harmless re-read
    bf16x8 na[4], nb0, nb1;
#pragma unroll
    for (int m = 0; m < 4; ++m) na[m] = *(const bf16x8*)(Ap[m] + off);
    nb0 = *(const bf16x8*)(Bp0 + off);
    nb1 = *(const bf16x8*)(Bp1 + off);
#pragma unroll
    for (int m = 0; m < 4; ++m) {
      acc[m][0] = mfma16(a[m], b0, acc[m][0]);
      acc[m][1] = mfma16(a[m], b1, acc[m][1]);
    }
#pragma unroll
    for (int m = 0; m < 4; ++m) a[m] = na[m];
    b0 = nb0; b1 = nb1;
  }
#pragma unroll
  for (int m = 0; m < 4; ++m)
#pragma unroll
    for (int t = 0; t < 2; ++t)
#pragma unroll
      for (int r = 0; r < 4; ++r)
        Z1[((size_t)ks * BN + Mb * 256 + m * 64 + w * 16 + quad * 4 + r) * DD
           + ns * 32 + t * 16 + m15] = acc[m][t][r];
}

// ---- k_epi1: h = dropout(relu(dis*z+b1)); Y2 = dis*(h@W2) -> Y2sT bf16 ---
__global__ __launch_bounds__(256) void k_epi1(const float* __restrict__ Z1,
    const unsigned short* __restrict__ Y1s, const float* __restrict__ dis,
    const float* __restrict__ b1, const float* __restrict__ W2,
    unsigned short* __restrict__ Y2sT)
{
  __shared__ float hs[64 * 65];
  __shared__ float W2l[DD * CC];
  const int tid = threadIdx.x;
  const int r0 = blockIdx.x * 64;
  const int b = r0 >> 11, kr0 = r0 & (NN - 1);
  *(float4*)(W2l + tid * 4) = *(const float4*)(W2 + tid * 4);   // 1024 floats
  const int n = tid & 63, wg = tid >> 6;
  const float bias = b1[n];
#pragma unroll
  for (int i = 0; i < 16; ++i) {
    const int rl = wg * 16 + i;
    const size_t row = (size_t)r0 + rl;
    const size_t o = row * DD + n;
    float z = bf2f(Y1s[o]);                          // diag (self-loop) term
#pragma unroll
    for (int p = 0; p < KS1; ++p) z += Z1[((size_t)p * BN + row) * DD + n];
    float h = fmaxf(dis[row] * z + bias, 0.f);
    const unsigned bits = tf_bits((unsigned)o);
    h = (bits >> 31) ? 0.f : (h + h);                // p=0.5, scale 2
    hs[rl * 65 + n] = h;
  }
  __syncthreads();
  const int c = tid & 15, rg = tid >> 4;             // 16 cols x 16 row-groups
  float y[4];
#pragma unroll
  for (int rr = 0; rr < 4; ++rr) {
    const int rl = rg * 4 + rr;
    float s = 0.f;
#pragma unroll
    for (int k = 0; k < 64; ++k) s += hs[rl * 65 + k] * W2l[k * CC + c];
    y[rr] = dis[r0 + rl] * s;
  }
  u16x4 pk = { f2bf(y[0]), f2bf(y[1]), f2bf(y[2]), f2bf(y[3]) };
  *(u16x4*)(Y2sT + ((size_t)b * CC + c) * NN + kr0 + rg * 4) = pk;
}

// ---- k_gemm2: Z2[ks] = Abf @ Y2 (bf16 MFMA), 4M x 1N per wave, KS2=16 ----
// block = 4 waves = 256 rows x 16 cols; grid = 64 Mb x 16 KS = 1024.
__global__ __launch_bounds__(256, 4) void k_gemm2(const unsigned short* __restrict__ Abf,
    const unsigned short* __restrict__ Y2sT, float* __restrict__ Z2)
{
  const int Mb = blockIdx.x >> 4;                 // 0..63
  const int ks = blockIdx.x & 15;                 // K split (128 K)
  const int w = __builtin_amdgcn_readfirstlane((int)threadIdx.x >> 6);
  const int lane = threadIdx.x & 63;
  const int m15 = lane & 15, quad = lane >> 4;
  const int b = Mb >> 3;
  const int k0 = ks * 128 + quad * 8;
  const unsigned short* Ap[4];
#pragma unroll
  for (int m = 0; m < 4; ++m)
    Ap[m] = Abf + ((size_t)Mb * 256 + m * 64 + w * 16 + m15) * NN + k0;
  const unsigned short* Bp = Y2sT + ((size_t)b * CC + m15) * NN + k0;
  const f32x4 zero = 0.f;
  f32x4 acc[4];
#pragma unroll
  for (int m = 0; m < 4; ++m) acc[m] = zero;
  bf16x8 a[4], bb;
#pragma unroll
  for (int m = 0; m < 4; ++m) a[m] = *(const bf16x8*)Ap[m];
  bb = *(const bf16x8*)Bp;
#pragma unroll 1
  for (int kk = 0; kk < 4; ++kk) {
    const int off = (kk < 3) ? (kk + 1) * 32 : 0;
    bf16x8 na[4], nbb;
#pragma unroll
    for (int m = 0; m < 4; ++m) na[m] = *(const bf16x8*)(Ap[m] + off);
    nbb = *(const bf16x8*)(Bp + off);
#pragma unroll
    for (int m = 0; m < 4; ++m) acc[m] = mfma16(a[m], bb, acc[m]);
#pragma unroll
    for (int m = 0; m < 4; ++m) a[m] = na[m];
    bb = nbb;
  }
#pragma unroll
  for (int m = 0; m < 4; ++m)
#pragma unroll
    for (int r = 0; r < 4; ++r)
      Z2[((size_t)ks * BN + Mb * 256 + m * 64 + w * 16 + quad * 4 + r) * CC + m15] = acc[m][r];
}

// ---- k_final: out = dis*(sum Z2p + Y2diag) + b2 --------------------------
__global__ __launch_bounds__(256) void k_final(const float* __restrict__ Z2,
    const unsigned short* __restrict__ Y2sT, const float* __restrict__ dis,
    const float* __restrict__ b2, float* __restrict__ out)
{
  const int r = blockIdx.x * 256 + threadIdx.x;
  const int b = r >> 11, kr = r & (NN - 1);
  float s[16];
#pragma unroll
  for (int c = 0; c < 16; ++c) s[c] = bf2f(Y2sT[((size_t)b * CC + c) * NN + kr]);
#pragma unroll
  for (int p = 0; p < KS2; ++p)
#pragma unroll
    for (int q = 0; q < 4; ++q) {
      float4 v = *(const float4*)(Z2 + ((size_t)p * BN + r) * CC + q * 4);
      s[q*4+0] += v.x; s[q*4+1] += v.y; s[q*4+2] += v.z; s[q*4+3] += v.w;
    }
  const float dv = dis[r];
#pragma unroll
  for (int q = 0; q < 4; ++q) {
    float4 o4;
    o4.x = dv * s[q*4+0] + b2[q*4+0];
    o4.y = dv * s[q*4+1] + b2[q*4+1];
    o4.z = dv * s[q*4+2] + b2[q*4+2];
    o4.w = dv * s[q*4+3] + b2[q*4+3];
    *(float4*)(out + (size_t)r * CC + q * 4) = o4;
  }
}

// ==================== FALLBACK fp32 PATH (R3, proven) ====================
#define FKS1 4
#define FKS2 16

__global__ __launch_bounds__(256) void d_deg_xw(const float* __restrict__ A,
    const float* __restrict__ X, const float* __restrict__ W1,
    float* __restrict__ dis, float* __restrict__ Y1s)
{
  const int w = threadIdx.x >> 6, lane = threadIdx.x & 63;
  const int row = __builtin_amdgcn_readfirstlane(blockIdx.x * 4 + w);
  const float4* Arow = (const float4*)(A + (size_t)row * NN);
  float s = 0.f;
#pragma unroll
  for (int it = 0; it < 8; ++it) {
    float4 v = Arow[lane + 64 * it];
    s += v.x + v.y + v.z + v.w;
  }
#pragma unroll
  for (int m = 32; m; m >>= 1) s += __shfl_xor(s, m, 64);
  const float dv = 1.0f / sqrtf(s + 1.0f);
  if (lane == 0) dis[row] = dv;
  const float* Xr = X + (size_t)row * DD;
  float acc = 0.f;
#pragma unroll
  for (int k = 0; k < DD; ++k) acc += Xr[k] * W1[k * DD + lane];
  Y1s[(size_t)row * DD + lane] = dv * acc;
}

__global__ __launch_bounds__(256) void d_gemm1(const float* __restrict__ A,
    const float* __restrict__ Y1s, float* __restrict__ Z1)
{
  const int rb = blockIdx.x >> 2, ks = blockIdx.x & (FKS1 - 1);
  const int lane = threadIdx.x & 63;
  const int c0 = __builtin_amdgcn_readfirstlane((threadIdx.x >> 6) << 4);
  const int row = rb * 64 + lane;
  const int batch = rb >> 5;
  const int KSEG = NN / FKS1;
  const float* Arow = A + (size_t)row * NN + ks * KSEG;
  const float* Yb = Y1s + (size_t)batch * NN * DD + c0;
  const int kbase = ks * KSEG;
  float acc[16];
#pragma unroll
  for (int c = 0; c < 16; ++c) acc[c] = 0.f;
  float4 a0 = *(const float4*)(Arow);
  float4 a1 = *(const float4*)(Arow + 4);
  float4 a2 = *(const float4*)(Arow + 8);
  float4 a3 = *(const float4*)(Arow + 12);
  for (int k = 0; k < KSEG; k += 16) {
    const int kn = (k + 16 < KSEG) ? (k + 16) : 0;
    float4 n0 = *(const float4*)(Arow + kn);
    float4 n1 = *(const float4*)(Arow + kn + 4);
    float4 n2 = *(const float4*)(Arow + kn + 8);
    float4 n3 = *(const float4*)(Arow + kn + 12);
    const float* y0 = Yb + (size_t)(kbase + k) * DD;
    const float av[16] = {a0.x, a0.y, a0.z, a0.w, a1.x, a1.y, a1.z, a1.w,
                          a2.x, a2.y, a2.z, a2.w, a3.x, a3.y, a3.z, a3.w};
#pragma unroll
    for (int j = 0; j < 16; ++j) {
      const float* yr = y0 + j * DD;
#pragma unroll
      for (int c = 0; c < 16; ++c) acc[c] += av[j] * yr[c];
    }
    a0 = n0; a1 = n1; a2 = n2; a3 = n3;
  }
  float* Zp = Z1 + ((size_t)ks * BN + row) * DD + c0;
#pragma unroll
  for (int c = 0; c < 16; c += 4) {
    float4 v; v.x = acc[c]; v.y = acc[c+1]; v.z = acc[c+2]; v.w = acc[c+3];
    *(float4*)(Zp + c) = v;
  }
}

__global__ __launch_bounds__(256) void d_epi1(const float* __restrict__ Z1,
    const float* __restrict__ Y1s, const float* __restrict__ dis,
    const float* __restrict__ b1, const float* __restrict__ W2,
    float* __restrict__ Y2s)
{
  __shared__ float W2l[DD * CC];
  __shared__ float hl[4][DD];
  const int tid = threadIdx.x;
  *(float4*)(W2l + tid * 4) = *(const float4*)(W2 + tid * 4);
  const int w = tid >> 6, lane = tid & 63;
  const int row = blockIdx.x * 4 + w;
  const size_t o = (size_t)row * DD + lane;
  float z = Y1s[o];
#pragma unroll
  for (int p = 0; p < FKS1; ++p) z += Z1[(size_t)p * BN * DD + o];
  const float dv = dis[row];
  float h = fmaxf(dv * z + b1[lane], 0.f);
  const unsigned bits = tf_bits((unsigned)o);
  h = (bits >> 31) ? 0.f : (h + h);
  hl[w][lane] = h;
  __syncthreads();
  const int wr = tid >> 6, l = tid & 63;
  const int c = l & 15, kq = l >> 4;
  float p = 0.f;
#pragma unroll
  for (int kk = 0; kk < 16; ++kk)
    p += hl[wr][kq * 16 + kk] * W2l[(kq * 16 + kk) * CC + c];
  p += __shfl_xor(p, 16, 64);
  p += __shfl_xor(p, 32, 64);
  if (l < 16) {
    const int rg = blockIdx.x * 4 + wr;
    Y2s[(size_t)rg * CC + c] = dis[rg] * p;
  }
}

__global__ __launch_bounds__(256) void d_gemm2(const float* __restrict__ A,
    const float* __restrict__ Y2s, float* __restrict__ Z2)
{
  const int rb = blockIdx.x >> 4, ks = blockIdx.x & (FKS2 - 1);
  const int row = rb * 256 + threadIdx.x;
  const int batch = rb >> 3;
  const int KSEG = NN / FKS2;
  const float* Arow = A + (size_t)row * NN + ks * KSEG;
  const float* Yb = Y2s + (size_t)batch * NN * CC;
  const int kbase = ks * KSEG;
  float acc[16];
#pragma unroll
  for (int c = 0; c < 16; ++c) acc[c] = 0.f;
  float4 a0 = *(const float4*)(Arow);
  float4 a1 = *(const float4*)(Arow + 4);
  for (int k = 0; k < KSEG; k += 8) {
    const int kn = (k + 8 < KSEG) ? (k + 8) : 0;
    float4 n0 = *(const float4*)(Arow + kn);
    float4 n1 = *(const float4*)(Arow + kn + 4);
    const float av[8] = {a0.x, a0.y, a0.z, a0.w, a1.x, a1.y, a1.z, a1.w};
#pragma unroll
    for (int j = 0; j < 8; ++j) {
      const float* yr = Yb + (size_t)(kbase + k + j) * CC;
#pragma unroll
      for (int c = 0; c < 16; ++c) acc[c] += av[j] * yr[c];
    }
    a0 = n0; a1 = n1;
  }
  float* Zp = Z2 + ((size_t)ks * BN + row) * CC;
#pragma unroll
  for (int c = 0; c < 16; c += 4) {
    float4 v; v.x = acc[c]; v.y = acc[c+1]; v.z = acc[c+2]; v.w = acc[c+3];
    *(float4*)(Zp + c) = v;
  }
}

__global__ __launch_bounds__(256) void d_final(const float* __restrict__ Z2,
    const float* __restrict__ Y2s, const float* __restrict__ dis,
    const float* __restrict__ b2, float* __restrict__ out)
{
  const int gid = blockIdx.x * 256 + threadIdx.x;
  const int r = gid >> 2, q = gid & 3;
  const size_t o = (size_t)r * CC + q * 4;
  float4 s = *(const float4*)(Y2s + o);
#pragma unroll
  for (int p = 0; p < FKS2; ++p) {
    const float4 zp = *(const float4*)(Z2 + (size_t)p * BN * CC + o);
    s.x += zp.x; s.y += zp.y; s.z += zp.z; s.w += zp.w;
  }
  const float dv = dis[r];
  const float4 bb = *(const float4*)(b2 + q * 4);
  float4 res;
  res.x = dv * s.x + bb.x;
  res.y = dv * s.y + bb.y;
  res.z = dv * s.z + bb.z;
  res.w = dv * s.w + bb.w;
  *(float4*)(out + o) = res;
}

extern "C" void kernel_launch(void* const* d_in, const int* in_sizes, int n_in,
                              void* d_out, int out_size, void* d_ws, size_t ws_size,
                              hipStream_t stream) {
  const float* X  = (const float*)d_in[0];
  const float* A  = (const float*)d_in[1];
  const float* W1 = (const float*)d_in[2];
  const float* b1 = (const float*)d_in[3];
  const float* W2 = (const float*)d_in[4];
  const float* b2 = (const float*)d_in[5];
  float* out = (float*)d_out;
  char* wsb = (char*)d_ws;

  // ws layout (bytes): Abf 64MB | Z1 32MB (Z2 16MB aliases) | dis 64KB |
  // Y1s 2MB | Y1sT 2MB | Y2sT 0.5MB  => 105,447,424 total
  const size_t NEED = 105447424;
  if (ws_size >= NEED) {
    unsigned short* Abf  = (unsigned short*)wsb;
    float*          Z1   = (float*)(wsb + 67108864);
    float*          Z2   = Z1;                          // aliases (Z1 dead)
    float*          dis  = (float*)(wsb + 100663296);
    unsigned short* Y1s  = (unsigned short*)(wsb + 100728832);
    unsigned short* Y1sT = (unsigned short*)(wsb + 102825984);
    unsigned short* Y2sT = (unsigned short*)(wsb + 104923136);

    k_deg  <<<BN / 4,  256, 0, stream>>>(A, dis, Abf);
    k_xw1  <<<BN / 64, 256, 0, stream>>>(X, W1, dis, Y1s, Y1sT);
    k_gemm1<<<1024,    256, 0, stream>>>(Abf, Y1sT, Z1);
    k_epi1 <<<BN / 64, 256, 0, stream>>>(Z1, Y1s, dis, b1, W2, Y2sT);
    k_gemm2<<<1024,    256, 0, stream>>>(Abf, Y2sT, Z2);
    k_final<<<BN / 256, 256, 0, stream>>>(Z2, Y2sT, dis, b2, out);
  } else {
    // fallback: proven fp32 path (R3)
    float* ws  = (float*)d_ws;
    float* dis = ws;
    float* Y1s = ws + 16384;
    float* Z1  = Y1s + (size_t)BN * DD;
    float* Z2  = Z1;
    float* Y2s = Z1 + (size_t)FKS1 * BN * DD;

    d_deg_xw<<<BN / 4,     256, 0, stream>>>(A, X, W1, dis, Y1s);
    d_gemm1 <<<256 * FKS1, 256, 0, stream>>>(A, Y1s, Z1);
    d_epi1  <<<BN / 4,     256, 0, stream>>>(Z1, Y1s, dis, b1, W2, Y2s);
    d_gemm2 <<<64 * FKS2,  256, 0, stream>>>(A, Y2s, Z2);
    d_final <<<256,        256, 0, stream>>>(Z2, Y2s, dis, b2, out);
  }
}

// Round 6
// 274.618 us; speedup vs baseline: 1.0121x; 1.0121x over previous
//
#include <hip/hip_runtime.h>

#define BN 16384   // B*N rows
#define NN 2048    // N
#define DD 64      // hidden
#define CC 16      // classes
#define KS1 8      // K-splits gemm1
#define KS2 16     // K-splits gemm2

typedef short bf16x8 __attribute__((ext_vector_type(8)));
typedef float f32x4 __attribute__((ext_vector_type(4)));
typedef unsigned short u16x4 __attribute__((ext_vector_type(4)));

__device__ __forceinline__ f32x4 mfma16(bf16x8 a, bf16x8 b, f32x4 c) {
  return __builtin_amdgcn_mfma_f32_16x16x32_bf16(a, b, c, 0, 0, 0);
}
__device__ __forceinline__ unsigned short f2bf(float f) {   // RNE
  unsigned u = __float_as_uint(f);
  return (unsigned short)((u + 0x7FFFu + ((u >> 16) & 1u)) >> 16);
}
__device__ __forceinline__ float bf2f(unsigned short h) {
  return __uint_as_float(((unsigned)h) << 16);
}

// ---------------- threefry-2x32 dropout mask (JAX key(42)) ----------------
__device__ __forceinline__ unsigned tf_bits(unsigned i) {
  unsigned x0 = 0u;
  unsigned x1 = i;
  const unsigned k0 = 0u, k1 = 42u, k2 = 0x1BD11BDAu ^ 0u ^ 42u;
  x0 += k0; x1 += k1;
#define TFR(r) { x0 += x1; x1 = (x1 << (r)) | (x1 >> (32 - (r))); x1 ^= x0; }
  TFR(13) TFR(15) TFR(26) TFR(6)
  x0 += k1; x1 += k2 + 1u;
  TFR(17) TFR(29) TFR(16) TFR(24)
  x0 += k2; x1 += k0 + 2u;
  TFR(13) TFR(15) TFR(26) TFR(6)
  x0 += k0; x1 += k1 + 3u;
  TFR(17) TFR(29) TFR(16) TFR(24)
  x0 += k1; x1 += k2 + 4u;
  TFR(13) TFR(15) TFR(26) TFR(6)
  x0 += k2; x1 += k0 + 5u;
#undef TFR
  return x0 ^ x1;
}

// ==================== bf16-MFMA PATH ====================

// ---- k_deg: degrees + A->bf16 + Y1 = dis*(X@W1) (fused; one pass over A) -
// wave per row (4096 blocks). After xor-reduce, lane = output col of Y1.
__global__ __launch_bounds__(256) void k_deg(const float* __restrict__ A,
    const float* __restrict__ X, const float* __restrict__ W1,
    float* __restrict__ dis, unsigned short* __restrict__ Abf,
    unsigned short* __restrict__ Y1s, unsigned short* __restrict__ Y1sT)
{
  const int w = threadIdx.x >> 6, lane = threadIdx.x & 63;
  const size_t row = (size_t)blockIdx.x * 4 + w;
  const float4* Arow = (const float4*)(A + row * NN);
  unsigned short* Brow = Abf + row * NN;
  float s = 0.f;
#pragma unroll
  for (int it = 0; it < 8; ++it) {
    float4 v = Arow[lane + 64 * it];
    s += (v.x + v.y) + (v.z + v.w);
    u16x4 p = { f2bf(v.x), f2bf(v.y), f2bf(v.z), f2bf(v.w) };
    *(u16x4*)(Brow + lane * 4 + it * 256) = p;
  }
#pragma unroll
  for (int m = 32; m; m >>= 1) s += __shfl_xor(s, m, 64);
  const float dv = 1.0f / sqrtf(s + 1.0f);   // A_tilda = A + I
  if (lane == 0) dis[row] = dv;
  // Y1 row (fp32 accumulate): X row is wave-uniform -> scalar loads
  const float* Xr = X + row * DD;
  float acc = 0.f;
#pragma unroll
  for (int k = 0; k < DD; ++k) acc += Xr[k] * W1[k * DD + lane];
  const unsigned short yv = f2bf(dv * acc);
  Y1s[row * DD + lane] = yv;
  const int b = (int)(row >> 11), kr = (int)(row & (NN - 1));
  Y1sT[((size_t)b * DD + lane) * NN + kr] = yv;     // transposed (B-operand)
}

// ---- k_gemm1: Z1[ks] = Abf @ Y1 (bf16 MFMA), 4M x 2N per wave, KS1=8 -----
// UNCHANGED from R5. grid = 64 Mb x 2 Nhalf x 8 KS = 1024.
__global__ __launch_bounds__(256, 4) void k_gemm1(const unsigned short* __restrict__ Abf,
    const unsigned short* __restrict__ Y1sT, float* __restrict__ Z1)
{
  const int Mb = blockIdx.x >> 4;                 // 0..63 (256-row tiles)
  const int ns = (blockIdx.x >> 3) & 1;           // N half (32 cols)
  const int ks = blockIdx.x & 7;                  // K split (256 K)
  const int w = __builtin_amdgcn_readfirstlane((int)threadIdx.x >> 6);
  const int lane = threadIdx.x & 63;
  const int m15 = lane & 15, quad = lane >> 4;
  const int b = Mb >> 3;                          // 8 blocks per batch
  const int k0 = ks * 256 + quad * 8;
  const unsigned short* Ap[4];
#pragma unroll
  for (int m = 0; m < 4; ++m)
    Ap[m] = Abf + ((size_t)Mb * 256 + m * 64 + w * 16 + m15) * NN + k0;
  const unsigned short* Bp0 = Y1sT + ((size_t)b * DD + ns * 32 + m15) * NN + k0;
  const unsigned short* Bp1 = Bp0 + (size_t)16 * NN;
  const f32x4 zero = 0.f;
  f32x4 acc[4][2];
#pragma unroll
  for (int m = 0; m < 4; ++m) { acc[m][0] = zero; acc[m][1] = zero; }
  bf16x8 a[4], b0, b1;
#pragma unroll
  for (int m = 0; m < 4; ++m) a[m] = *(const bf16x8*)Ap[m];
  b0 = *(const bf16x8*)Bp0;
  b1 = *(const bf16x8*)Bp1;
#pragma unroll 1
  for (int kk = 0; kk < 8; ++kk) {
    const int off = (kk < 7) ? (kk + 1) * 32 : 0;  // wrap: harmless re-read
    bf16x8 na[4], nb0, nb1;
#pragma unroll
    for (int m = 0; m < 4; ++m) na[m] = *(const bf16x8*)(Ap[m] + off);
    nb0 = *(const bf16x8*)(Bp0 + off);
    nb1 = *(const bf16x8*)(Bp1 + off);
#pragma unroll
    for (int m = 0; m < 4; ++m) {
      acc[m][0] = mfma16(a[m], b0, acc[m][0]);
      acc[m][1] = mfma16(a[m], b1, acc[m][1]);
    }
#pragma unroll
    for (int m = 0; m < 4; ++m) a[m] = na[m];
    b0 = nb0; b1 = nb1;
  }
#pragma unroll
  for (int m = 0; m < 4; ++m)
#pragma unroll
    for (int t = 0; t < 2; ++t)
#pragma unroll
      for (int r = 0; r < 4; ++r)
        Z1[((size_t)ks * BN + Mb * 256 + m * 64 + w * 16 + quad * 4 + r) * DD
           + ns * 32 + t * 16 + m15] = acc[m][t][r];
}

// ---- k_epi1: h = dropout(relu(dis*z+b1)); Y2 = dis*(h@W2) -> Y2sT bf16 ---
// 16 rows/block, grid 1024 (4 blocks/CU). Thread: 4 h-elements, 1 output.
__global__ __launch_bounds__(256) void k_epi1(const float* __restrict__ Z1,
    const unsigned short* __restrict__ Y1s, const float* __restrict__ dis,
    const float* __restrict__ b1, const float* __restrict__ W2,
    unsigned short* __restrict__ Y2sT)
{
  __shared__ float hs[16][65];
  __shared__ float W2l[DD * CC];
  const int tid = threadIdx.x;
  *(float4*)(W2l + tid * 4) = *(const float4*)(W2 + tid * 4);   // 1024 floats
  const int r0 = blockIdx.x * 16;
#pragma unroll
  for (int j = 0; j < 4; ++j) {
    const int e = tid + j * 256;                   // 0..1023 = 16 rows x 64
    const int rl = e >> 6, n = e & 63;
    const size_t row = (size_t)r0 + rl;
    const size_t o = row * DD + n;
    float z = bf2f(Y1s[o]);                        // diag (self-loop) term
#pragma unroll
    for (int p = 0; p < KS1; ++p) z += Z1[((size_t)p * BN + row) * DD + n];
    float h = fmaxf(dis[row] * z + b1[n], 0.f);
    const unsigned bits = tf_bits((unsigned)o);
    hs[rl][n] = (bits >> 31) ? 0.f : (h + h);      // p=0.5, scale 2
  }
  __syncthreads();
  const int c = tid & 15, rl = tid >> 4;           // 256 = 16 rows x 16 cols
  float s = 0.f;
#pragma unroll
  for (int k = 0; k < DD; ++k) s += hs[rl][k] * W2l[k * CC + c];
  const int row = r0 + rl;
  const int b = row >> 11, kr = row & (NN - 1);
  Y2sT[((size_t)b * CC + c) * NN + kr] = f2bf(dis[row] * s);
}

// ---- k_gemm2: Z2[ks] = Abf @ Y2 (bf16 MFMA), 4M x 1N per wave, KS2=16 ----
// UNCHANGED from R5. grid = 64 Mb x 16 KS = 1024.
__global__ __launch_bounds__(256, 4) void k_gemm2(const unsigned short* __restrict__ Abf,
    const unsigned short* __restrict__ Y2sT, float* __restrict__ Z2)
{
  const int Mb = blockIdx.x >> 4;                 // 0..63
  const int ks = blockIdx.x & 15;                 // K split (128 K)
  const int w = __builtin_amdgcn_readfirstlane((int)threadIdx.x >> 6);
  const int lane = threadIdx.x & 63;
  const int m15 = lane & 15, quad = lane >> 4;
  const int b = Mb >> 3;
  const int k0 = ks * 128 + quad * 8;
  const unsigned short* Ap[4];
#pragma unroll
  for (int m = 0; m < 4; ++m)
    Ap[m] = Abf + ((size_t)Mb * 256 + m * 64 + w * 16 + m15) * NN + k0;
  const unsigned short* Bp = Y2sT + ((size_t)b * CC + m15) * NN + k0;
  const f32x4 zero = 0.f;
  f32x4 acc[4];
#pragma unroll
  for (int m = 0; m < 4; ++m) acc[m] = zero;
  bf16x8 a[4], bb;
#pragma unroll
  for (int m = 0; m < 4; ++m) a[m] = *(const bf16x8*)Ap[m];
  bb = *(const bf16x8*)Bp;
#pragma unroll 1
  for (int kk = 0; kk < 4; ++kk) {
    const int off = (kk < 3) ? (kk + 1) * 32 : 0;
    bf16x8 na[4], nbb;
#pragma unroll
    for (int m = 0; m < 4; ++m) na[m] = *(const bf16x8*)(Ap[m] + off);
    nbb = *(const bf16x8*)(Bp + off);
#pragma unroll
    for (int m = 0; m < 4; ++m) acc[m] = mfma16(a[m], bb, acc[m]);
#pragma unroll
    for (int m = 0; m < 4; ++m) a[m] = na[m];
    bb = nbb;
  }
#pragma unroll
  for (int m = 0; m < 4; ++m)
#pragma unroll
    for (int r = 0; r < 4; ++r)
      Z2[((size_t)ks * BN + Mb * 256 + m * 64 + w * 16 + quad * 4 + r) * CC + m15] = acc[m][r];
}

// ---- k_final: out = dis*(sum Z2p + Y2diag) + b2 --------------------------
// thread per (row, col-quad): 65536 threads / 256 blocks; 16 indep float4 loads.
__global__ __launch_bounds__(256) void k_final(const float* __restrict__ Z2,
    const unsigned short* __restrict__ Y2sT, const float* __restrict__ dis,
    const float* __restrict__ b2, float* __restrict__ out)
{
  const int gid = blockIdx.x * 256 + threadIdx.x;   // 65536 float4 groups
  const int r = gid >> 2, q = gid & 3;
  const int b = r >> 11, kr = r & (NN - 1);
  float4 s;
  s.x = bf2f(Y2sT[((size_t)b * CC + q * 4 + 0) * NN + kr]);
  s.y = bf2f(Y2sT[((size_t)b * CC + q * 4 + 1) * NN + kr]);
  s.z = bf2f(Y2sT[((size_t)b * CC + q * 4 + 2) * NN + kr]);
  s.w = bf2f(Y2sT[((size_t)b * CC + q * 4 + 3) * NN + kr]);
#pragma unroll
  for (int p = 0; p < KS2; ++p) {
    const float4 zp = *(const float4*)(Z2 + ((size_t)p * BN + r) * CC + q * 4);
    s.x += zp.x; s.y += zp.y; s.z += zp.z; s.w += zp.w;
  }
  const float dv = dis[r];
  const float4 bb = *(const float4*)(b2 + q * 4);
  float4 res;
  res.x = dv * s.x + bb.x;
  res.y = dv * s.y + bb.y;
  res.z = dv * s.z + bb.z;
  res.w = dv * s.w + bb.w;
  *(float4*)(out + (size_t)r * CC + q * 4) = res;
}

// ==================== FALLBACK fp32 PATH (R3, proven) ====================
#define FKS1 4
#define FKS2 16

__global__ __launch_bounds__(256) void d_deg_xw(const float* __restrict__ A,
    const float* __restrict__ X, const float* __restrict__ W1,
    float* __restrict__ dis, float* __restrict__ Y1s)
{
  const int w = threadIdx.x >> 6, lane = threadIdx.x & 63;
  const int row = __builtin_amdgcn_readfirstlane(blockIdx.x * 4 + w);
  const float4* Arow = (const float4*)(A + (size_t)row * NN);
  float s = 0.f;
#pragma unroll
  for (int it = 0; it < 8; ++it) {
    float4 v = Arow[lane + 64 * it];
    s += v.x + v.y + v.z + v.w;
  }
#pragma unroll
  for (int m = 32; m; m >>= 1) s += __shfl_xor(s, m, 64);
  const float dv = 1.0f / sqrtf(s + 1.0f);
  if (lane == 0) dis[row] = dv;
  const float* Xr = X + (size_t)row * DD;
  float acc = 0.f;
#pragma unroll
  for (int k = 0; k < DD; ++k) acc += Xr[k] * W1[k * DD + lane];
  Y1s[(size_t)row * DD + lane] = dv * acc;
}

__global__ __launch_bounds__(256) void d_gemm1(const float* __restrict__ A,
    const float* __restrict__ Y1s, float* __restrict__ Z1)
{
  const int rb = blockIdx.x >> 2, ks = blockIdx.x & (FKS1 - 1);
  const int lane = threadIdx.x & 63;
  const int c0 = __builtin_amdgcn_readfirstlane((threadIdx.x >> 6) << 4);
  const int row = rb * 64 + lane;
  const int batch = rb >> 5;
  const int KSEG = NN / FKS1;
  const float* Arow = A + (size_t)row * NN + ks * KSEG;
  const float* Yb = Y1s + (size_t)batch * NN * DD + c0;
  const int kbase = ks * KSEG;
  float acc[16];
#pragma unroll
  for (int c = 0; c < 16; ++c) acc[c] = 0.f;
  float4 a0 = *(const float4*)(Arow);
  float4 a1 = *(const float4*)(Arow + 4);
  float4 a2 = *(const float4*)(Arow + 8);
  float4 a3 = *(const float4*)(Arow + 12);
  for (int k = 0; k < KSEG; k += 16) {
    const int kn = (k + 16 < KSEG) ? (k + 16) : 0;
    float4 n0 = *(const float4*)(Arow + kn);
    float4 n1 = *(const float4*)(Arow + kn + 4);
    float4 n2 = *(const float4*)(Arow + kn + 8);
    float4 n3 = *(const float4*)(Arow + kn + 12);
    const float* y0 = Yb + (size_t)(kbase + k) * DD;
    const float av[16] = {a0.x, a0.y, a0.z, a0.w, a1.x, a1.y, a1.z, a1.w,
                          a2.x, a2.y, a2.z, a2.w, a3.x, a3.y, a3.z, a3.w};
#pragma unroll
    for (int j = 0; j < 16; ++j) {
      const float* yr = y0 + j * DD;
#pragma unroll
      for (int c = 0; c < 16; ++c) acc[c] += av[j] * yr[c];
    }
    a0 = n0; a1 = n1; a2 = n2; a3 = n3;
  }
  float* Zp = Z1 + ((size_t)ks * BN + row) * DD + c0;
#pragma unroll
  for (int c = 0; c < 16; c += 4) {
    float4 v; v.x = acc[c]; v.y = acc[c+1]; v.z = acc[c+2]; v.w = acc[c+3];
    *(float4*)(Zp + c) = v;
  }
}

__global__ __launch_bounds__(256) void d_epi1(const float* __restrict__ Z1,
    const float* __restrict__ Y1s, const float* __restrict__ dis,
    const float* __restrict__ b1, const float* __restrict__ W2,
    float* __restrict__ Y2s)
{
  __shared__ float W2l[DD * CC];
  __shared__ float hl[4][DD];
  const int tid = threadIdx.x;
  *(float4*)(W2l + tid * 4) = *(const float4*)(W2 + tid * 4);
  const int w = tid >> 6, lane = tid & 63;
  const int row = blockIdx.x * 4 + w;
  const size_t o = (size_t)row * DD + lane;
  float z = Y1s[o];
#pragma unroll
  for (int p = 0; p < FKS1; ++p) z += Z1[(size_t)p * BN * DD + o];
  const float dv = dis[row];
  float h = fmaxf(dv * z + b1[lane], 0.f);
  const unsigned bits = tf_bits((unsigned)o);
  h = (bits >> 31) ? 0.f : (h + h);
  hl[w][lane] = h;
  __syncthreads();
  const int wr = tid >> 6, l = tid & 63;
  const int c = l & 15, kq = l >> 4;
  float p = 0.f;
#pragma unroll
  for (int kk = 0; kk < 16; ++kk)
    p += hl[wr][kq * 16 + kk] * W2l[(kq * 16 + kk) * CC + c];
  p += __shfl_xor(p, 16, 64);
  p += __shfl_xor(p, 32, 64);
  if (l < 16) {
    const int rg = blockIdx.x * 4 + wr;
    Y2s[(size_t)rg * CC + c] = dis[rg] * p;
  }
}

__global__ __launch_bounds__(256) void d_gemm2(const float* __restrict__ A,
    const float* __restrict__ Y2s, float* __restrict__ Z2)
{
  const int rb = blockIdx.x >> 4, ks = blockIdx.x & (FKS2 - 1);
  const int row = rb * 256 + threadIdx.x;
  const int batch = rb >> 3;
  const int KSEG = NN / FKS2;
  const float* Arow = A + (size_t)row * NN + ks * KSEG;
  const float* Yb = Y2s + (size_t)batch * NN * CC;
  const int kbase = ks * KSEG;
  float acc[16];
#pragma unroll
  for (int c = 0; c < 16; ++c) acc[c] = 0.f;
  float4 a0 = *(const float4*)(Arow);
  float4 a1 = *(const float4*)(Arow + 4);
  for (int k = 0; k < KSEG; k += 8) {
    const int kn = (k + 8 < KSEG) ? (k + 8) : 0;
    float4 n0 = *(const float4*)(Arow + kn);
    float4 n1 = *(const float4*)(Arow + kn + 4);
    const float av[8] = {a0.x, a0.y, a0.z, a0.w, a1.x, a1.y, a1.z, a1.w};
#pragma unroll
    for (int j = 0; j < 8; ++j) {
      const float* yr = Yb + (size_t)(kbase + k + j) * CC;
#pragma unroll
      for (int c = 0; c < 16; ++c) acc[c] += av[j] * yr[c];
    }
    a0 = n0; a1 = n1;
  }
  float* Zp = Z2 + ((size_t)ks * BN + row) * CC;
#pragma unroll
  for (int c = 0; c < 16; c += 4) {
    float4 v; v.x = acc[c]; v.y = acc[c+1]; v.z = acc[c+2]; v.w = acc[c+3];
    *(float4*)(Zp + c) = v;
  }
}

__global__ __launch_bounds__(256) void d_final(const float* __restrict__ Z2,
    const float* __restrict__ Y2s, const float* __restrict__ dis,
    const float* __restrict__ b2, float* __restrict__ out)
{
  const int gid = blockIdx.x * 256 + threadIdx.x;
  const int r = gid >> 2, q = gid & 3;
  const size_t o = (size_t)r * CC + q * 4;
  float4 s = *(const float4*)(Y2s + o);
#pragma unroll
  for (int p = 0; p < FKS2; ++p) {
    const float4 zp = *(const float4*)(Z2 + (size_t)p * BN * CC + o);
    s.x += zp.x; s.y += zp.y; s.z += zp.z; s.w += zp.w;
  }
  const float dv = dis[r];
  const float4 bb = *(const float4*)(b2 + q * 4);
  float4 res;
  res.x = dv * s.x + bb.x;
  res.y = dv * s.y + bb.y;
  res.z = dv * s.z + bb.z;
  res.w = dv * s.w + bb.w;
  *(float4*)(out + o) = res;
}

extern "C" void kernel_launch(void* const* d_in, const int* in_sizes, int n_in,
                              void* d_out, int out_size, void* d_ws, size_t ws_size,
                              hipStream_t stream) {
  const float* X  = (const float*)d_in[0];
  const float* A  = (const float*)d_in[1];
  const float* W1 = (const float*)d_in[2];
  const float* b1 = (const float*)d_in[3];
  const float* W2 = (const float*)d_in[4];
  const float* b2 = (const float*)d_in[5];
  float* out = (float*)d_out;
  char* wsb = (char*)d_ws;

  // ws layout (bytes): Abf 64MB | Z1 32MB (Z2 16MB aliases) | dis 64KB |
  // Y1s 2MB | Y1sT 2MB | Y2sT 0.5MB  => 105,447,424 total
  const size_t NEED = 105447424;
  if (ws_size >= NEED) {
    unsigned short* Abf  = (unsigned short*)wsb;
    float*          Z1   = (float*)(wsb + 67108864);
    float*          Z2   = Z1;                          // aliases (Z1 dead)
    float*          dis  = (float*)(wsb + 100663296);
    unsigned short* Y1s  = (unsigned short*)(wsb + 100728832);
    unsigned short* Y1sT = (unsigned short*)(wsb + 102825984);
    unsigned short* Y2sT = (unsigned short*)(wsb + 104923136);

    k_deg  <<<BN / 4,  256, 0, stream>>>(A, X, W1, dis, Abf, Y1s, Y1sT);
    k_gemm1<<<1024,    256, 0, stream>>>(Abf, Y1sT, Z1);
    k_epi1 <<<BN / 16, 256, 0, stream>>>(Z1, Y1s, dis, b1, W2, Y2sT);
    k_gemm2<<<1024,    256, 0, stream>>>(Abf, Y2sT, Z2);
    k_final<<<256,     256, 0, stream>>>(Z2, Y2sT, dis, b2, out);
  } else {
    // fallback: proven fp32 path (R3)
    float* ws  = (float*)d_ws;
    float* dis = ws;
    float* Y1s = ws + 16384;
    float* Z1  = Y1s + (size_t)BN * DD;
    float* Z2  = Z1;
    float* Y2s = Z1 + (size_t)FKS1 * BN * DD;

    d_deg_xw<<<BN / 4,     256, 0, stream>>>(A, X, W1, dis, Y1s);
    d_gemm1 <<<256 * FKS1, 256, 0, stream>>>(A, Y1s, Z1);
    d_epi1  <<<BN / 4,     256, 0, stream>>>(Z1, Y1s, dis, b1, W2, Y2s);
    d_gemm2 <<<64 * FKS2,  256, 0, stream>>>(A, Y2s, Z2);
    d_final <<<256,        256, 0, stream>>>(Z2, Y2s, dis, b2, out);
  }
}